// Round 3
// baseline (98.545 us; speedup 1.0000x reference)
//
#include <hip/hip_runtime.h>
#include <hip/hip_bf16.h>

#define NFEATS 128

typedef __attribute__((ext_vector_type(8))) short bf16x8;
typedef __attribute__((ext_vector_type(4))) float f32x4;
typedef __attribute__((ext_vector_type(4))) short short4v;

__device__ inline short f2bf(float f) {
    union { float f; unsigned u; } c; c.f = f;
    unsigned u = c.u;
    return (short)((u + 0x7FFFu + ((u >> 16) & 1u)) >> 16);  // RNE
}
__device__ inline float bf2f(short v) {
    union { unsigned u; float f; } c;
    c.u = ((unsigned)(unsigned short)v) << 16;
    return c.f;
}

// Fused precompute for both tables, grid-strided so W is staged ONCE per block:
//   first half of grid : A[n,j] = sum_k item[n,k] * W1[j,   k] + b1[j]
//   second half        : B[n,j] = sum_k user[n,k] * W1[j,128+k]
// Out stored bf16. Each tile = 128 rows x 128 cols, K=128 in one shot.
__global__ __launch_bounds__(256) void precompute_kernel(
    const float* __restrict__ item, const float* __restrict__ user,
    const float* __restrict__ W1, const float* __restrict__ b1,
    short* __restrict__ A, short* __restrict__ B,
    int n_nodes, int nblk_half)
{
    const int which = (blockIdx.x >= nblk_half) ? 1 : 0;
    const int tloc  = blockIdx.x - which * nblk_half;
    const float* __restrict__ X = which ? user : item;
    short* __restrict__ Out = which ? B : A;
    const int k_off4 = which ? 32 : 0;   // in float4 units (128 floats)

    // W tile in LDS: stride 136 bf16 = 272 B (16B-aligned rows, bank stride 4 -> 2-way, free)
    __shared__ short Wlds[128][136];
    const int tid = threadIdx.x;

    // Stage W via float4 loads (16 per thread), short4 ds_writes.
    const float4* W4 = (const float4*)W1;   // row stride 64 float4
    for (int i = tid; i < 128 * 32; i += 256) {
        int j = i >> 5, c = i & 31;
        float4 w = W4[j * 64 + k_off4 + c];
        short4v p;
        p[0] = f2bf(w.x); p[1] = f2bf(w.y); p[2] = f2bf(w.z); p[3] = f2bf(w.w);
        *(short4v*)&Wlds[j][c * 4] = p;
    }

    const int wave = tid >> 6, lane = tid & 63;
    const int r16 = lane & 15, q = lane >> 4;       // q in 0..3

    // Bias per output col (A table only) — hoisted out of the tile loop.
    float bv[8];
#pragma unroll
    for (int n = 0; n < 8; ++n) bv[n] = which ? 0.f : b1[n * 16 + r16];

    __syncthreads();

    const int n_tiles = (n_nodes + 127) >> 7;

    for (int t = tloc; t < n_tiles; t += nblk_half) {
        const int row_base = t * 128 + wave * 32;

        // A-fragments: X rows -> bf16, lane holds X[row][kk*32 + q*8 + j], j=0..7
        bf16x8 afrag[2][4];
#pragma unroll
        for (int m = 0; m < 2; ++m) {
            int row = row_base + m * 16 + r16;
            if (row >= n_nodes) row = n_nodes - 1;      // clamp (stores predicated)
            const float* xr = X + (size_t)row * NFEATS;
#pragma unroll
            for (int kk = 0; kk < 4; ++kk) {
                int k0 = kk * 32 + q * 8;
                float4 lo = *(const float4*)(xr + k0);
                float4 hi = *(const float4*)(xr + k0 + 4);
                bf16x8 f;
                f[0] = f2bf(lo.x); f[1] = f2bf(lo.y); f[2] = f2bf(lo.z); f[3] = f2bf(lo.w);
                f[4] = f2bf(hi.x); f[5] = f2bf(hi.y); f[6] = f2bf(hi.z); f[7] = f2bf(hi.w);
                afrag[m][kk] = f;
            }
        }

        f32x4 acc[2][8];
#pragma unroll
        for (int n = 0; n < 8; ++n) {
            f32x4 init = {bv[n], bv[n], bv[n], bv[n]};
            acc[0][n] = init;
            acc[1][n] = init;
        }

#pragma unroll
        for (int n = 0; n < 8; ++n) {
#pragma unroll
            for (int kk = 0; kk < 4; ++kk) {
                // B operand: lane holds W[col=n*16+r16][k = kk*32 + q*8 + j]
                bf16x8 wf = *(const bf16x8*)&Wlds[n * 16 + r16][kk * 32 + q * 8];
                acc[0][n] = __builtin_amdgcn_mfma_f32_16x16x32_bf16(afrag[0][kk], wf, acc[0][n], 0, 0, 0);
                acc[1][n] = __builtin_amdgcn_mfma_f32_16x16x32_bf16(afrag[1][kk], wf, acc[1][n], 0, 0, 0);
            }
        }

        // C/D layout: col = lane&15, row = (lane>>4)*4 + r
#pragma unroll
        for (int m = 0; m < 2; ++m) {
#pragma unroll
            for (int r = 0; r < 4; ++r) {
                int row = row_base + m * 16 + q * 4 + r;
                if (row < n_nodes) {
                    short* orow = Out + (size_t)row * NFEATS;
#pragma unroll
                    for (int n = 0; n < 8; ++n)
                        orow[n * 16 + r16] = f2bf(acc[m][n][r]);
                }
            }
        }
        // No barrier needed between tiles: Wlds is read-only after staging.
    }
}

// Edge stage: score[e] = dot(relu(A[src[e]] + B[dst[e]]), w2) + b2
// One quarter-wave (16 lanes) per edge, 2 edges in flight per iteration.
__global__ __launch_bounds__(256) void edge_kernel(
    const short* __restrict__ A, const short* __restrict__ B,
    const int* __restrict__ src, const int* __restrict__ dst,
    const float* __restrict__ W2, const float* __restrict__ b2,
    float* __restrict__ out, int n_edges)
{
    const int t = blockIdx.x * 256 + threadIdx.x;
    const int lane16 = threadIdx.x & 15;

    float w2v[8];
#pragma unroll
    for (int j = 0; j < 8; ++j) w2v[j] = W2[lane16 * 8 + j];
    const float b2v = b2[0];

    const int qw = t >> 4;
    const int nqw = (gridDim.x * 256) >> 4;

    for (int e0 = qw; e0 < n_edges; e0 += 2 * nqw) {
        const int e1 = e0 + nqw;
        const bool has1 = e1 < n_edges;

        int s0 = src[e0], d0 = dst[e0];
        int s1 = has1 ? src[e1] : s0;
        int d1 = has1 ? dst[e1] : d0;

        bf16x8 av0 = *(const bf16x8*)(A + (size_t)s0 * NFEATS + lane16 * 8);
        bf16x8 bv0 = *(const bf16x8*)(B + (size_t)d0 * NFEATS + lane16 * 8);
        bf16x8 av1 = *(const bf16x8*)(A + (size_t)s1 * NFEATS + lane16 * 8);
        bf16x8 bv1 = *(const bf16x8*)(B + (size_t)d1 * NFEATS + lane16 * 8);

        float acc0 = 0.f, acc1 = 0.f;
#pragma unroll
        for (int j = 0; j < 8; ++j) {
            float h0 = bf2f(av0[j]) + bf2f(bv0[j]);
            h0 = fmaxf(h0, 0.f);
            acc0 = fmaf(h0, w2v[j], acc0);
            float h1 = bf2f(av1[j]) + bf2f(bv1[j]);
            h1 = fmaxf(h1, 0.f);
            acc1 = fmaf(h1, w2v[j], acc1);
        }
#pragma unroll
        for (int sh = 1; sh <= 8; sh <<= 1) {
            acc0 += __shfl_xor(acc0, sh);
            acc1 += __shfl_xor(acc1, sh);
        }
        if (lane16 == 0) {
            out[e0] = acc0 + b2v;
            if (has1) out[e1] = acc1 + b2v;
        }
    }
}

extern "C" void kernel_launch(void* const* d_in, const int* in_sizes, int n_in,
                              void* d_out, int out_size, void* d_ws, size_t ws_size,
                              hipStream_t stream) {
    const float* item = (const float*)d_in[0];
    const float* user = (const float*)d_in[1];
    const float* W1   = (const float*)d_in[2];
    const float* b1   = (const float*)d_in[3];
    const float* W2   = (const float*)d_in[4];
    const float* b2   = (const float*)d_in[5];
    const int*   src  = (const int*)d_in[6];
    const int*   dst  = (const int*)d_in[7];
    float* out = (float*)d_out;

    const int n_nodes = in_sizes[0] / NFEATS;
    const int n_edges = in_sizes[6];

    short* A = (short*)d_ws;                         // [n_nodes][128] bf16
    short* B = A + (size_t)n_nodes * NFEATS;         // [n_nodes][128] bf16

    const int n_tiles = (n_nodes + 127) / 128;
    const int nblk_half = (n_tiles + 1) / 2;         // each block does 2 tiles
    precompute_kernel<<<2 * nblk_half, 256, 0, stream>>>(
        item, user, W1, b1, A, B, n_nodes, nblk_half);

    edge_kernel<<<2048, 256, 0, stream>>>(A, B, src, dst, W2, b2, out, n_edges);
}

// Round 4
// 89.067 us; speedup vs baseline: 1.1064x; 1.1064x over previous
//
#include <hip/hip_runtime.h>
#include <hip/hip_bf16.h>

#define NFEATS 128

typedef __attribute__((ext_vector_type(8))) short bf16x8;
typedef __attribute__((ext_vector_type(4))) float f32x4;
typedef __attribute__((ext_vector_type(4))) short short4v;

__device__ inline short f2bf(float f) {
    union { float f; unsigned u; } c; c.f = f;
    unsigned u = c.u;
    return (short)((u + 0x7FFFu + ((u >> 16) & 1u)) >> 16);  // RNE
}
__device__ inline float bf2f(short v) {
    union { unsigned u; float f; } c;
    c.u = ((unsigned)(unsigned short)v) << 16;
    return c.f;
}

// Fused precompute for both tables (blockIdx.y selects):
//   y == 0: A[n,j] = sum_k item[n,k] * W1[j,   k] + b1[j]
//   y == 1: B[n,j] = sum_k user[n,k] * W1[j,128+k]
// Out stored bf16. One block = 512 threads = 8 waves = 256 rows; K=128 one shot.
// 34 KB LDS -> 4 blocks/CU x 8 waves = 32 waves/CU (occupancy cap removed vs
// 256-thread version which capped at 16 waves/CU).
__global__ __launch_bounds__(512) void precompute_kernel(
    const float* __restrict__ item, const float* __restrict__ user,
    const float* __restrict__ W1, const float* __restrict__ b1,
    short* __restrict__ A, short* __restrict__ B, int n_nodes)
{
    const int which = blockIdx.y;
    const float* __restrict__ X = which ? user : item;
    short* __restrict__ Out = which ? B : A;
    const int k_off4 = which ? 32 : 0;   // in float4 units (128 floats)

    // W tile in LDS: stride 136 bf16 = 272 B (16B-aligned rows, bank-friendly)
    __shared__ short Wlds[128][136];
    const int tid = threadIdx.x;

    // Stage W via float4 loads (8 per thread), short4 ds_writes.
    const float4* W4 = (const float4*)W1;   // row stride 64 float4
    for (int i = tid; i < 128 * 32; i += 512) {
        int j = i >> 5, c = i & 31;
        float4 w = W4[j * 64 + k_off4 + c];
        short4v p;
        p[0] = f2bf(w.x); p[1] = f2bf(w.y); p[2] = f2bf(w.z); p[3] = f2bf(w.w);
        *(short4v*)&Wlds[j][c * 4] = p;
    }
    __syncthreads();

    const int wave = tid >> 6, lane = tid & 63;
    const int r16 = lane & 15, q = lane >> 4;       // q in 0..3
    const int row_base = blockIdx.x * 256 + wave * 32;

    // A-fragments: X rows -> bf16, lane holds X[row][kk*32 + q*8 + j], j=0..7
    bf16x8 afrag[2][4];
#pragma unroll
    for (int m = 0; m < 2; ++m) {
        int row = row_base + m * 16 + r16;
        if (row >= n_nodes) row = n_nodes - 1;      // clamp (stores predicated)
        const float* xr = X + (size_t)row * NFEATS;
#pragma unroll
        for (int kk = 0; kk < 4; ++kk) {
            int k0 = kk * 32 + q * 8;
            float4 lo = *(const float4*)(xr + k0);
            float4 hi = *(const float4*)(xr + k0 + 4);
            bf16x8 f;
            f[0] = f2bf(lo.x); f[1] = f2bf(lo.y); f[2] = f2bf(lo.z); f[3] = f2bf(lo.w);
            f[4] = f2bf(hi.x); f[5] = f2bf(hi.y); f[6] = f2bf(hi.z); f[7] = f2bf(hi.w);
            afrag[m][kk] = f;
        }
    }

    // Accumulators init with b1[col] (MFMA C-in accumulates); B-table no bias.
    f32x4 acc[2][8];
#pragma unroll
    for (int n = 0; n < 8; ++n) {
        float bv = which ? 0.f : b1[n * 16 + r16];
        f32x4 init = {bv, bv, bv, bv};
        acc[0][n] = init;
        acc[1][n] = init;
    }

#pragma unroll
    for (int n = 0; n < 8; ++n) {
#pragma unroll
        for (int kk = 0; kk < 4; ++kk) {
            // B operand: lane holds W[col=n*16+r16][k = kk*32 + q*8 + j]
            bf16x8 wf = *(const bf16x8*)&Wlds[n * 16 + r16][kk * 32 + q * 8];
            acc[0][n] = __builtin_amdgcn_mfma_f32_16x16x32_bf16(afrag[0][kk], wf, acc[0][n], 0, 0, 0);
            acc[1][n] = __builtin_amdgcn_mfma_f32_16x16x32_bf16(afrag[1][kk], wf, acc[1][n], 0, 0, 0);
        }
    }

    // C/D layout: col = lane&15, row = (lane>>4)*4 + r
#pragma unroll
    for (int m = 0; m < 2; ++m) {
#pragma unroll
        for (int r = 0; r < 4; ++r) {
            int row = row_base + m * 16 + q * 4 + r;
            if (row < n_nodes) {
                short* orow = Out + (size_t)row * NFEATS;
#pragma unroll
                for (int n = 0; n < 8; ++n)
                    orow[n * 16 + r16] = f2bf(acc[m][n][r]);
            }
        }
    }
}

// Edge stage: score[e] = dot(relu(A[src[e]] + B[dst[e]]), w2) + b2
// One quarter-wave (16 lanes) per edge, 2 edges in flight per iteration.
__global__ __launch_bounds__(256) void edge_kernel(
    const short* __restrict__ A, const short* __restrict__ B,
    const int* __restrict__ src, const int* __restrict__ dst,
    const float* __restrict__ W2, const float* __restrict__ b2,
    float* __restrict__ out, int n_edges)
{
    const int t = blockIdx.x * 256 + threadIdx.x;
    const int lane16 = threadIdx.x & 15;

    float w2v[8];
#pragma unroll
    for (int j = 0; j < 8; ++j) w2v[j] = W2[lane16 * 8 + j];
    const float b2v = b2[0];

    const int qw = t >> 4;
    const int nqw = (gridDim.x * 256) >> 4;

    for (int e0 = qw; e0 < n_edges; e0 += 2 * nqw) {
        const int e1 = e0 + nqw;
        const bool has1 = e1 < n_edges;

        int s0 = src[e0], d0 = dst[e0];
        int s1 = has1 ? src[e1] : s0;
        int d1 = has1 ? dst[e1] : d0;

        bf16x8 av0 = *(const bf16x8*)(A + (size_t)s0 * NFEATS + lane16 * 8);
        bf16x8 bv0 = *(const bf16x8*)(B + (size_t)d0 * NFEATS + lane16 * 8);
        bf16x8 av1 = *(const bf16x8*)(A + (size_t)s1 * NFEATS + lane16 * 8);
        bf16x8 bv1 = *(const bf16x8*)(B + (size_t)d1 * NFEATS + lane16 * 8);

        float acc0 = 0.f, acc1 = 0.f;
#pragma unroll
        for (int j = 0; j < 8; ++j) {
            float h0 = bf2f(av0[j]) + bf2f(bv0[j]);
            h0 = fmaxf(h0, 0.f);
            acc0 = fmaf(h0, w2v[j], acc0);
            float h1 = bf2f(av1[j]) + bf2f(bv1[j]);
            h1 = fmaxf(h1, 0.f);
            acc1 = fmaf(h1, w2v[j], acc1);
        }
#pragma unroll
        for (int sh = 1; sh <= 8; sh <<= 1) {
            acc0 += __shfl_xor(acc0, sh);
            acc1 += __shfl_xor(acc1, sh);
        }
        if (lane16 == 0) {
            out[e0] = acc0 + b2v;
            if (has1) out[e1] = acc1 + b2v;
        }
    }
}

extern "C" void kernel_launch(void* const* d_in, const int* in_sizes, int n_in,
                              void* d_out, int out_size, void* d_ws, size_t ws_size,
                              hipStream_t stream) {
    const float* item = (const float*)d_in[0];
    const float* user = (const float*)d_in[1];
    const float* W1   = (const float*)d_in[2];
    const float* b1   = (const float*)d_in[3];
    const float* W2   = (const float*)d_in[4];
    const float* b2   = (const float*)d_in[5];
    const int*   src  = (const int*)d_in[6];
    const int*   dst  = (const int*)d_in[7];
    float* out = (float*)d_out;

    const int n_nodes = in_sizes[0] / NFEATS;
    const int n_edges = in_sizes[6];

    short* A = (short*)d_ws;                         // [n_nodes][128] bf16
    short* B = A + (size_t)n_nodes * NFEATS;         // [n_nodes][128] bf16

    const int nblk = (n_nodes + 255) / 256;          // 256 rows per block
    dim3 grid(nblk, 2);
    precompute_kernel<<<grid, 512, 0, stream>>>(item, user, W1, b1, A, B, n_nodes);

    edge_kernel<<<2048, 256, 0, stream>>>(A, B, src, dst, W2, b2, out, n_edges);
}

// Round 5
// 80.463 us; speedup vs baseline: 1.2247x; 1.1069x over previous
//
#include <hip/hip_runtime.h>
#include <hip/hip_bf16.h>
#include <stdint.h>

#define NFEATS 128

typedef __attribute__((ext_vector_type(8))) short bf16x8;
typedef __attribute__((ext_vector_type(4))) float f32x4;
typedef __attribute__((ext_vector_type(4))) short short4v;

__device__ inline short f2bf(float f) {
    union { float f; unsigned u; } c; c.f = f;
    unsigned u = c.u;
    return (short)((u + 0x7FFFu + ((u >> 16) & 1u)) >> 16);  // RNE
}
__device__ inline float bf2f(short v) {
    union { unsigned u; float f; } c;
    c.u = ((unsigned)(unsigned short)v) << 16;
    return c.f;
}

// Fused precompute for both tables (blockIdx.y selects):
//   y == 0: A[n,j] = sum_k item[n,k] * W1[j,   k] + b1[j]
//   y == 1: B[n,j] = sum_k user[n,k] * W1[j,128+k]
// Canonical staging: W -> LDS once -> W frags lifted to registers; X tiles
// (64 rows x 128 f32 = 32 KB) staged via global_load_lds (linear LDS dest,
// XOR-swizzled GLOBAL source so swizzled ds_read_b128 frags are conflict-lite),
// double-buffered (buf0 recycles the W region). 8 waves: wave = (rowgrp 0..3,
// colhalf 0..1) -> 16 rows x 64 cols per wave, 16 MFMA per tile.
__global__ __launch_bounds__(512, 4) void precompute_kernel(
    const float* __restrict__ item, const float* __restrict__ user,
    const float* __restrict__ W1, const float* __restrict__ b1,
    short* __restrict__ A, short* __restrict__ B, int n_nodes)
{
    __shared__ __align__(1024) uint8_t lds[34816 + 32768];  // [W/buf0 | buf1]

    const int which = blockIdx.y;
    const float* __restrict__ X = which ? user : item;
    short* __restrict__ Out = which ? B : A;
    const int k_off4 = which ? 32 : 0;   // in float4 units (128 floats)

    const int tid = threadIdx.x;
    const int w = tid >> 6, lane = tid & 63;
    const int r16 = lane & 15, q = lane >> 4;     // q in 0..3
    const int rowgrp = w >> 1, colhalf = w & 1;

    // ---- stage W (fp32 -> bf16) into padded LDS ----
    {
        short (*Wl)[136] = (short (*)[136])lds;
        const float4* W4 = (const float4*)W1;     // row stride 64 float4
        for (int i = tid; i < 128 * 32; i += 512) {
            int j = i >> 5, c = i & 31;
            float4 wv = W4[j * 64 + k_off4 + c];
            short4v p;
            p[0] = f2bf(wv.x); p[1] = f2bf(wv.y); p[2] = f2bf(wv.z); p[3] = f2bf(wv.w);
            *(short4v*)&Wl[j][c * 4] = p;
        }
    }
    __syncthreads();

    // ---- lift this wave's W fragments + bias into registers ----
    bf16x8 wfrag[4][4];
    float bias[4];
    {
        short (*Wl)[136] = (short (*)[136])lds;
#pragma unroll
        for (int n = 0; n < 4; ++n) {
            int col = colhalf * 64 + n * 16 + r16;
#pragma unroll
            for (int kk = 0; kk < 4; ++kk)
                wfrag[n][kk] = *(const bf16x8*)&Wl[col][kk * 32 + q * 8];
            bias[n] = which ? 0.f : b1[col];
        }
    }
    __syncthreads();   // W region now reusable as X buffer 0

    const int n_tiles = (n_nodes + 63) >> 6;

    // Stage one 64-row tile into buffer `buf` (linear LDS, swizzled global src).
    // Storage rule: X[row r][16B-chunk c] lives at LDS r*512 + (c^(r&7))*16.
    auto stage = [&](int buf, int t) {
        uint8_t* base = lds + buf * 34816;
#pragma unroll
        for (int i = 0; i < 4; ++i) {
            int o = (w << 12) + (i << 10) + (lane << 4);   // linear byte off in tile
            int r = o >> 9;
            int c_lds = (o >> 4) & 31;
            int node = (t << 6) + r;
            if (node >= n_nodes) node = n_nodes - 1;       // clamp (stores predicated)
            const uint8_t* gp = (const uint8_t*)X + (size_t)node * 512
                              + (size_t)(((c_lds ^ (r & 7)) << 4));
            auto g1 = (const __attribute__((address_space(1))) uint32_t*)gp;
            auto l3 = (__attribute__((address_space(3))) uint32_t*)(base + (w << 12) + (i << 10));
            __builtin_amdgcn_global_load_lds(g1, l3, 16, 0, 0);
        }
    };

    int t = blockIdx.x;
    if (t < n_tiles) stage(0, t);
    int cur = 0;

    for (; t < n_tiles; t += gridDim.x) {
        __syncthreads();                         // drains vmcnt -> buf[cur] ready
        int tn = t + gridDim.x;
        if (tn < n_tiles) stage(cur ^ 1, tn);    // async prefetch next tile

        // ---- fragments from buf[cur] (swizzled ds_read_b128) ----
        const uint8_t* base = lds + cur * 34816;
        const int r = rowgrp * 16 + r16;
        const uint8_t* rowp = base + r * 512;
        const int s = r & 7;
        bf16x8 afrag[4];
#pragma unroll
        for (int kk = 0; kk < 4; ++kk) {
            int c0 = kk * 8 + q * 2;
            float4 v0 = *(const float4*)(rowp + ((c0 ^ s) << 4));
            float4 v1 = *(const float4*)(rowp + (((c0 + 1) ^ s) << 4));
            bf16x8 f;
            f[0] = f2bf(v0.x); f[1] = f2bf(v0.y); f[2] = f2bf(v0.z); f[3] = f2bf(v0.w);
            f[4] = f2bf(v1.x); f[5] = f2bf(v1.y); f[6] = f2bf(v1.z); f[7] = f2bf(v1.w);
            afrag[kk] = f;
        }

        f32x4 acc[4];
#pragma unroll
        for (int n = 0; n < 4; ++n) {
            f32x4 init = {bias[n], bias[n], bias[n], bias[n]};
            acc[n] = init;
        }
#pragma unroll
        for (int n = 0; n < 4; ++n)
#pragma unroll
            for (int kk = 0; kk < 4; ++kk)
                acc[n] = __builtin_amdgcn_mfma_f32_16x16x32_bf16(afrag[kk], wfrag[n][kk], acc[n], 0, 0, 0);

        // C/D layout: col = lane&15, row = (lane>>4)*4 + rr
        const int row0 = (t << 6) + rowgrp * 16 + q * 4;
#pragma unroll
        for (int rr = 0; rr < 4; ++rr) {
            int row = row0 + rr;
            if (row < n_nodes) {
                short* orow = Out + (size_t)row * NFEATS;
#pragma unroll
                for (int n = 0; n < 4; ++n)
                    orow[colhalf * 64 + n * 16 + r16] = f2bf(acc[n][rr]);
            }
        }
        cur ^= 1;
    }
}

// Edge stage: score[e] = dot(relu(A[src[e]] + B[dst[e]]), w2) + b2
// One quarter-wave (16 lanes) per edge, 2 edges in flight per iteration.
__global__ __launch_bounds__(256) void edge_kernel(
    const short* __restrict__ A, const short* __restrict__ B,
    const int* __restrict__ src, const int* __restrict__ dst,
    const float* __restrict__ W2, const float* __restrict__ b2,
    float* __restrict__ out, int n_edges)
{
    const int t = blockIdx.x * 256 + threadIdx.x;
    const int lane16 = threadIdx.x & 15;

    float w2v[8];
#pragma unroll
    for (int j = 0; j < 8; ++j) w2v[j] = W2[lane16 * 8 + j];
    const float b2v = b2[0];

    const int qw = t >> 4;
    const int nqw = (gridDim.x * 256) >> 4;

    for (int e0 = qw; e0 < n_edges; e0 += 2 * nqw) {
        const int e1 = e0 + nqw;
        const bool has1 = e1 < n_edges;

        int s0 = src[e0], d0 = dst[e0];
        int s1 = has1 ? src[e1] : s0;
        int d1 = has1 ? dst[e1] : d0;

        bf16x8 av0 = *(const bf16x8*)(A + (size_t)s0 * NFEATS + lane16 * 8);
        bf16x8 bv0 = *(const bf16x8*)(B + (size_t)d0 * NFEATS + lane16 * 8);
        bf16x8 av1 = *(const bf16x8*)(A + (size_t)s1 * NFEATS + lane16 * 8);
        bf16x8 bv1 = *(const bf16x8*)(B + (size_t)d1 * NFEATS + lane16 * 8);

        float acc0 = 0.f, acc1 = 0.f;
#pragma unroll
        for (int j = 0; j < 8; ++j) {
            float h0 = bf2f(av0[j]) + bf2f(bv0[j]);
            h0 = fmaxf(h0, 0.f);
            acc0 = fmaf(h0, w2v[j], acc0);
            float h1 = bf2f(av1[j]) + bf2f(bv1[j]);
            h1 = fmaxf(h1, 0.f);
            acc1 = fmaf(h1, w2v[j], acc1);
        }
#pragma unroll
        for (int sh = 1; sh <= 8; sh <<= 1) {
            acc0 += __shfl_xor(acc0, sh);
            acc1 += __shfl_xor(acc1, sh);
        }
        if (lane16 == 0) {
            out[e0] = acc0 + b2v;
            if (has1) out[e1] = acc1 + b2v;
        }
    }
}

extern "C" void kernel_launch(void* const* d_in, const int* in_sizes, int n_in,
                              void* d_out, int out_size, void* d_ws, size_t ws_size,
                              hipStream_t stream) {
    const float* item = (const float*)d_in[0];
    const float* user = (const float*)d_in[1];
    const float* W1   = (const float*)d_in[2];
    const float* b1   = (const float*)d_in[3];
    const float* W2   = (const float*)d_in[4];
    const float* b2   = (const float*)d_in[5];
    const int*   src  = (const int*)d_in[6];
    const int*   dst  = (const int*)d_in[7];
    float* out = (float*)d_out;

    const int n_nodes = in_sizes[0] / NFEATS;
    const int n_edges = in_sizes[6];

    short* A = (short*)d_ws;                         // [n_nodes][128] bf16
    short* B = A + (size_t)n_nodes * NFEATS;         // [n_nodes][128] bf16

    dim3 grid(256, 2);                               // 512 blocks = 2/CU resident
    precompute_kernel<<<grid, 512, 0, stream>>>(item, user, W1, b1, A, B, n_nodes);

    edge_kernel<<<2048, 256, 0, stream>>>(A, B, src, dst, W2, b2, out, n_edges);
}